// Round 1
// baseline (56.193 us; speedup 1.0000x reference)
//
#include <hip/hip_runtime.h>

#define T_LEN 2000
#define BATCH 32
#define ALPHA 1024
#define BLANK 0

// Kernel 1: argmax over alphabet axis. One 64-lane wave per (t,b) row.
// x layout: [t][b][a] (row = t*BATCH + b, contiguous in a).
// Writes ml transposed to [b][t] in workspace for kernel 2's per-batch scan.
__global__ __launch_bounds__(256) void ctc_argmax_kernel(
    const float* __restrict__ x, int* __restrict__ ml)
{
    const int wave = threadIdx.x >> 6;
    const int lane = threadIdx.x & 63;
    const int row  = blockIdx.x * 4 + wave;      // row = t*BATCH + b
    if (row >= T_LEN * BATCH) return;

    const float4* rp = (const float4*)(x + (size_t)row * ALPHA);

    float best = -INFINITY;
    int   bidx = 0;
    #pragma unroll
    for (int p = 0; p < 4; ++p) {
        float4 v = rp[p * 64 + lane];            // coalesced: 1KB/wave/instr
        int base = (p * 64 + lane) * 4;
        // indices increase monotonically per lane -> strict '>' keeps the
        // first occurrence (matches jnp.argmax tie-break) within a lane
        if (v.x > best) { best = v.x; bidx = base;     }
        if (v.y > best) { best = v.y; bidx = base + 1; }
        if (v.z > best) { best = v.z; bidx = base + 2; }
        if (v.w > best) { best = v.w; bidx = base + 3; }
    }

    // wave butterfly reduce: larger value wins; on tie, smaller index
    #pragma unroll
    for (int off = 32; off > 0; off >>= 1) {
        float ov = __shfl_xor(best, off);
        int   oi = __shfl_xor(bidx, off);
        if (ov > best || (ov == best && oi < bidx)) { best = ov; bidx = oi; }
    }

    if (lane == 0) {
        int t = row / BATCH;
        int b = row - t * BATCH;
        ml[b * T_LEN + t] = bidx;
    }
}

// Kernel 2: per-batch CTC compaction. One wave per batch element.
__global__ __launch_bounds__(64) void ctc_compact_kernel(
    const int* __restrict__ ml, const int* __restrict__ lengths,
    int* __restrict__ out)
{
    const int b    = blockIdx.x;
    const int lane = threadIdx.x;

    int len = lengths[b];
    if (len > T_LEN) len = T_LEN;
    if (len < 0)     len = 0;

    const int* row = ml  + b * T_LEN;
    int*       tok = out + b * T_LEN;

    int offset     = 0;    // running count of kept symbols
    int carry_prev = -1;   // ml value at the last position of prior chunk

    const int NCHUNK = (T_LEN + 63) / 64;   // 32
    for (int c = 0; c < NCHUNK; ++c) {
        int t = c * 64 + lane;
        int m = (t < T_LEN) ? row[t] : BLANK;

        int prev = __shfl_up(m, 1);
        if (lane == 0) prev = carry_prev;

        bool keep = (t < len) && (m != BLANK) && (m != prev);

        unsigned long long mask = __ballot(keep);
        int pos = offset + __popcll(mask & ((1ull << lane) - 1ull));
        if (keep) tok[pos] = m;

        offset    += __popcll(mask);
        carry_prev = __shfl(m, 63);
    }

    // tail fill with -1: positions [offset, T) — disjoint from scatter above
    for (int t = offset + lane; t < T_LEN; t += 64) tok[t] = -1;

    if (lane == 0) out[BATCH * T_LEN + b] = offset;  // out_lengths
}

extern "C" void kernel_launch(void* const* d_in, const int* in_sizes, int n_in,
                              void* d_out, int out_size, void* d_ws, size_t ws_size,
                              hipStream_t stream) {
    const float* x       = (const float*)d_in[0];
    const int*   lengths = (const int*)d_in[1];
    int*         out     = (int*)d_out;
    int*         ml      = (int*)d_ws;   // B*T int32 = 256 KB scratch

    const int nrows = T_LEN * BATCH;     // 64000 rows
    ctc_argmax_kernel<<<(nrows + 3) / 4, 256, 0, stream>>>(x, ml);
    ctc_compact_kernel<<<BATCH, 64, 0, stream>>>(ml, lengths, out);
}